// Round 1
// baseline (61.229 us; speedup 1.0000x reference)
//
#include <hip/hip_runtime.h>
#include <math.h>

namespace {

constexpr int NCH   = 32;     // channels
constexpr int NG    = 2048;   // grid points
constexpr int BATCH = 32;
constexpr float DXC = 0.08f;

constexpr int NSEG   = 8;             // output segments per row (blocks per b)
constexpr int SEGLEN = NG / NSEG;     // 256 m-values per block
constexpr int NCHUNK = 32;            // chunks over the full row
constexpr int CHL    = NG / NCHUNK;   // 64 elements per chunk
constexpr int NSUB   = 8;             // subchunks per chunk
constexpr int SUBL   = CHL / NSUB;    // 8 elements per subchunk
constexpr int CPS    = NCHUNK / NSEG; // chunks per segment = 4

// out[b,m,c] = s_c * (F[m] + G[m] - x[m])
//   F[m] = x[m] + r_c F[m-1]   (forward scan)
//   G[m] = x[m] + r_c G[m+1]   (backward scan)
//   r_c = exp(-DX/w_c), s_c = DX/(2 w_c), w_c = 0.1 + 4.9*sigmoid(eta_c)
__global__ __launch_bounds__(1024)
void egc_kernel(const float* __restrict__ inputs,
                const float* __restrict__ eta,
                float* __restrict__ out) {
    __shared__ float xs[NG];                 // 8 KB: full input row
    __shared__ float F8[CPS][NSUB][NCH];     // 4 KB: local fwd scan @ subchunk ends (own segment)
    __shared__ float G8[CPS][NSUB][NCH];     // 4 KB: local bwd scan @ subchunk starts (own segment)
    __shared__ float Ef[NCHUNK][NCH];        // 4 KB: per-chunk total fwd carry
    __shared__ float Eb[NCHUNK][NCH];        // 4 KB: per-chunk total bwd carry
    __shared__ float CF[NCHUNK][NCH];        // 4 KB: full F entering chunk (value at chunk*64 - 1)
    __shared__ float CB[NCHUNK][NCH];        // 4 KB: full G just past chunk end (value at chunk*64+64)

    const int tid = threadIdx.x;
    const int c   = tid & 31;        // channel (fast index -> coalesced c-writes)
    const int t   = tid >> 5;        // chunk-thread [0,32)
    const int bid = blockIdx.x;
    const int b   = bid >> 3;        // batch row
    const int seg = bid & (NSEG - 1);

    // per-channel parameters
    const float e   = eta[c];
    const float sig = 1.0f / (1.0f + expf(-e));
    const float w   = 0.1f + 4.9f * sig;
    const float lam = DXC / w;
    const float r   = expf(-lam);
    const float s   = 0.5f * DXC / w;

    // ---- phase 0: stage full input row to LDS (coalesced) ----
    const float* xrow = inputs + (size_t)b * NG;
    xs[tid]        = xrow[tid];
    xs[tid + 1024] = xrow[tid + 1024];
    __syncthreads();

    // ---- phase 1: local scans of chunk t (length 64), record sub-carries every 8 ----
    {
        const int base = t * CHL;
        const int tc   = t - seg * CPS;              // local chunk idx if in our segment
        const bool own = (tc >= 0) && (tc < CPS);
        float f = 0.0f;
#pragma unroll
        for (int i = 0; i < CHL; ++i) {
            f = fmaf(r, f, xs[base + i]);
            if ((i & (SUBL - 1)) == SUBL - 1) {
                if (own) F8[tc][i >> 3][c] = f;
            }
        }
        Ef[t][c] = f;                                // total chunk fwd carry
        float g = 0.0f;
#pragma unroll
        for (int i = CHL - 1; i >= 0; --i) {
            g = fmaf(r, g, xs[base + i]);
            if ((i & (SUBL - 1)) == 0) {
                if (own) G8[tc][i >> 3][c] = g;
            }
        }
        Eb[t][c] = g;                                // total chunk bwd carry
    }
    __syncthreads();

    // ---- phase 2: chunk-level carry scans (wave 0 = forward, wave 1 = backward) ----
    {
        const float rho = expf(-lam * (float)CHL);   // r^64
        if (t == 0) {                                // lanes 0..31 of wave 0
            float fe = 0.0f;
            for (int k = 0; k < NCHUNK; ++k) {
                CF[k][c] = fe;
                fe = fmaf(rho, fe, Ef[k][c]);
            }
        } else if (t == 2) {                         // lanes 0..31 of wave 1
            float ge = 0.0f;
            for (int k = NCHUNK - 1; k >= 0; --k) {
                CB[k][c] = ge;
                ge = fmaf(rho, ge, Eb[k][c]);
            }
        }
    }
    __syncthreads();

    // ---- phase 3: finalize 8 outputs of subchunk T = seg*32 + t ----
    const int T     = seg * (SEGLEN / SUBL) + t;     // global subchunk index
    const int chunk = T >> 3;                        // in [seg*CPS, seg*CPS + CPS)
    const int sub   = T & (NSUB - 1);
    const int tc    = chunk - seg * CPS;
    const int m0    = T * SUBL;

    // exact carry into position m0 (forward) and out of position m0+7 (backward)
    float fin = CF[chunk][c] * expf(-lam * (float)(SUBL * sub));
    if (sub > 0) fin += F8[tc][sub - 1][c];
    float gin;
    if (sub < NSUB - 1)
        gin = G8[tc][sub + 1][c] + CB[chunk][c] * expf(-lam * (float)(CHL - SUBL * (sub + 1)));
    else
        gin = CB[chunk][c];

    float xv[SUBL], Fv[SUBL];
#pragma unroll
    for (int i = 0; i < SUBL; ++i) xv[i] = xs[m0 + i];

    float f = fin;
#pragma unroll
    for (int i = 0; i < SUBL; ++i) { f = fmaf(r, f, xv[i]); Fv[i] = f; }

    float g = gin;
    float* orow = out + (size_t)b * NG * NCH;
#pragma unroll
    for (int i = SUBL - 1; i >= 0; --i) {
        g = fmaf(r, g, xv[i]);
        orow[(size_t)(m0 + i) * NCH + c] = s * (Fv[i] + g - xv[i]);
    }
}

} // namespace

extern "C" void kernel_launch(void* const* d_in, const int* in_sizes, int n_in,
                              void* d_out, int out_size, void* d_ws, size_t ws_size,
                              hipStream_t stream) {
    const float* inputs = (const float*)d_in[0];
    // d_in[1] = grids (uniform spacing DX, unused: |x_n - x_m| = |n-m|*DX)
    const float* eta    = (const float*)d_in[2];
    float* out          = (float*)d_out;

    dim3 grid(BATCH * NSEG);   // 256 blocks: (b, segment)
    dim3 block(1024);          // (32 channels) x (32 chunk-threads)
    hipLaunchKernelGGL(egc_kernel, grid, block, 0, stream, inputs, eta, out);
}